// Round 7
// baseline (300.163 us; speedup 1.0000x reference)
//
#include <hip/hip_runtime.h>
#include <hip/hip_bf16.h>
#include <cstdint>

// Problem: B=128, T=512, F=512, M=512 (fixed by setup_inputs).
// out[b,m,f] = gelu( sum_t xn[b,t,f]*W[m,t] + bias[m] ) + x[b,m,f]
// xn = layernorm over t per (b,f), * gamma[t] + beta[t].

#define B_ 128
#define T_ 512
#define F_ 512
#define M_ 512
#define FT 64           // f-tile per block (round-7: 32 -> 64, halves Wq L2 re-stream)
#define XN_STRIDE 520   // bf16 elems per f-row of xnS (512 + 8 pad)

typedef __attribute__((ext_vector_type(8))) short bf16x8;
typedef __attribute__((ext_vector_type(4))) float f32x4;

static __device__ __forceinline__ unsigned short f2bf(float f) {
    unsigned int u = __float_as_uint(f);
    unsigned int r = u + 0x7FFFu + ((u >> 16) & 1u);
    return (unsigned short)(r >> 16);
}

// tanh-form GELU folded to y * sigmoid(u): ~7 VALU ops, |err| vs exact ~5e-4
// (negligible next to the 0.03125 bf16-GEMM absmax; round-6 verified).
static __device__ __forceinline__ float gelu_fast(float y) {
    float y2 = y * y;
    float u  = y * (-1.5957691216057308f - 0.07135481283262997f * y2);
    float s  = __expf(u);
    return y * __builtin_amdgcn_rcpf(1.0f + s);
}

// ---------------- W fp32 -> bf16 convert + fragment-major permute ----------------
// Wq chunks [kc(16)][mg(32)][lane(64)]: chunk = W[m=mg*16+(lane&15)][k=kc*32+(lane>>4)*8..+8)
// -> A-fragment load = ONE coalesced 1 KB global_load_dwordx4.
__global__ void wconv_kernel(const float* __restrict__ W, unsigned short* __restrict__ Wq) {
    int idx  = blockIdx.x * 256 + threadIdx.x;   // one 16 B chunk per thread; 32768 total
    int lane = idx & 63;
    int mg   = (idx >> 6) & 31;
    int kc   = idx >> 11;
    int m = mg * 16 + (lane & 15);
    int k = kc * 32 + (lane >> 4) * 8;
    const float* src = W + (size_t)m * 512 + k;
    float4 v0 = *(const float4*)(src);
    float4 v1 = *(const float4*)(src + 4);
    uint4 o;
    o.x = (unsigned int)f2bf(v0.x) | ((unsigned int)f2bf(v0.y) << 16);
    o.y = (unsigned int)f2bf(v0.z) | ((unsigned int)f2bf(v0.w) << 16);
    o.z = (unsigned int)f2bf(v1.x) | ((unsigned int)f2bf(v1.y) << 16);
    o.w = (unsigned int)f2bf(v1.z) | ((unsigned int)f2bf(v1.w) << 16);
    *(uint4*)(Wq + (size_t)idx * 8) = o;
}

// ---------------- fused LN + GEMM + GELU + residual ------------------------------
// ROUND-7 STRUCTURE: FT=64 -> 1024 blocks; each block reads Wq once for 2x the
// output -> Wq L2 traffic 1 GB -> 512 MB; K-loop = 16 MFMA per 4 A-loads (2x density).
// LDS ~71 KB -> 2 blocks/CU, grid = exactly 2 rounds.
// Phase 3 re-reads x from L2/L3 instead of registers (tile just touched; epilogue's
// 3rd read already measured FETCH-free) -> GEMM-phase regs ~60 VGPR + 64 AGPR <= 128.
// ROUND-3 LESSON: never force a reg cap that spills (watch hbm_bytes!).
// ROUND-5 LESSON: keep the A-fragment register double-buffer (depth-1 prefetch).
// LDS layout:
//   [0,     66560)  xnS  : bf16 [64 f][520 t-stride]
//   [66560, 68608)  gS   : float[512] gamma
//   [68608, 70656)  bS   : float[512] beta
//   [70656, 70912)  meanS: float[64]
//   [70912, 71168)  rstdS: float[64]
// red_sum/red_sq (2 KB each, phases 1-2 only) ALIAS xnS[0..4096).
__global__ __launch_bounds__(512, 4) void timemix_main(
    const float* __restrict__ x, const float* __restrict__ gamma,
    const float* __restrict__ beta, const unsigned short* __restrict__ Wq,
    const float* __restrict__ bias, float* __restrict__ out)
{
    __shared__ __align__(16) unsigned char smem[71168];
    unsigned char* xnS = smem;                      // bf16 [64][520]
    float* gS    = (float*)(smem + 66560);
    float* bS    = (float*)(smem + 68608);
    float* meanS = (float*)(smem + 70656);
    float* rstdS = (float*)(smem + 70912);
    float* red_sum = (float*)(smem);                // aliases xnS bytes [0,2048)
    float* red_sq  = (float*)(smem + 2048);         // aliases xnS bytes [2048,4096)

    const int tid   = threadIdx.x;
    const int w     = tid >> 6;                     // wave id = t-group
    const int lane  = tid & 63;                     // = f within tile
    const int batch = blockIdx.y;
    const int f0    = blockIdx.x * FT;

    // phase 0: stage gamma/beta
    gS[tid] = gamma[tid];
    bS[tid] = beta[tid];

    // phase 1: wave w streams t in [w*64, w*64+64) of f-column (f0+lane);
    // 256 B fully-coalesced per wave-load; fp32 partial sum/sumsq only (no reg cache).
    const float* xb = x + ((size_t)batch * T_ + (size_t)w * 64) * F_ + f0 + lane;
    {
        float s = 0.f, q = 0.f;
        #pragma unroll
        for (int i = 0; i < 64; ++i) {
            float v = xb[(size_t)i * F_];
            s += v; q += v * v;
        }
        red_sum[w * 64 + lane] = s;
        red_sq [w * 64 + lane] = q;
    }
    __syncthreads();

    // phase 2: reduce 8 partials per f -> mean/rstd
    if (tid < 64) {
        float s = 0.f, q = 0.f;
        #pragma unroll
        for (int g = 0; g < 8; ++g) { s += red_sum[g * 64 + tid]; q += red_sq[g * 64 + tid]; }
        float mean = s * (1.0f / 512.0f);
        float var  = q * (1.0f / 512.0f) - mean * mean;
        meanS[tid] = mean;
        rstdS[tid] = rsqrtf(var + 1e-5f);
    }
    __syncthreads();

    // phase 3: re-read x (L2/L3-resident: just touched in phase 1), normalize fp32,
    // pack bf16, write xnS rows. Overwrites the dead red_* alias region.
    {
        const float mean = meanS[lane];
        const float rstd = rstdS[lane];
        unsigned char* xrow = xnS + (size_t)lane * (XN_STRIDE * 2);
        #pragma unroll
        for (int c = 0; c < 8; ++c) {
            const int t0 = w * 64 + c * 8;
            float v[8];
            #pragma unroll
            for (int i = 0; i < 8; ++i) v[i] = xb[(size_t)(c * 8 + i) * F_];
            unsigned int pr[4];
            #pragma unroll
            for (int h = 0; h < 4; ++h) {
                float a0 = rstd * gS[t0 + 2 * h];
                float v0 = v[2 * h] * a0 + (bS[t0 + 2 * h] - mean * a0);
                float a1 = rstd * gS[t0 + 2 * h + 1];
                float v1 = v[2 * h + 1] * a1 + (bS[t0 + 2 * h + 1] - mean * a1);
                pr[h] = (unsigned int)f2bf(v0) | ((unsigned int)f2bf(v1) << 16);
            }
            uint4 pk; pk.x = pr[0]; pk.y = pr[1]; pk.z = pr[2]; pk.w = pr[3];
            *(uint4*)(xrow + (size_t)t0 * 2) = pk;
        }
    }
    __syncthreads();  // last barrier; K-loop is barrier-free

    // GEMM: wave w owns output rows m in [64w, 64w+64), cols f0..f0+63 (4 f-tiles).
    // A-fragments from Wq with register double-buffer (prefetch depth 1);
    // 16 MFMA per 4 L2 loads per K-chunk.
    const int lr = lane & 15;
    const int q4 = lane >> 4;
    const unsigned short* wbase = Wq + ((size_t)(w * 4) * 64 + lane) * 8;
    // +kc*16384 elems per K-chunk, +mi*512 elems per m-tile

    f32x4 acc[4][4];
    #pragma unroll
    for (int mi = 0; mi < 4; ++mi)
        #pragma unroll
        for (int fi = 0; fi < 4; ++fi)
            acc[mi][fi] = (f32x4){0.f, 0.f, 0.f, 0.f};

    const unsigned char* bbase = xnS + (size_t)lr * (XN_STRIDE * 2) + q4 * 16;
    // +fi*16*(XN_STRIDE*2) per f-tile, +kc*64 per K-chunk

    bf16x8 aA[4], aB[4];
    #pragma unroll
    for (int mi = 0; mi < 4; ++mi)
        aA[mi] = *(const bf16x8*)(wbase + (size_t)mi * 512);

    for (int kc = 0; kc < 16; kc += 2) {
        // prefetch kc+1
        #pragma unroll
        for (int mi = 0; mi < 4; ++mi)
            aB[mi] = *(const bf16x8*)(wbase + (size_t)(kc + 1) * 16384 + (size_t)mi * 512);
        {
            bf16x8 b[4];
            #pragma unroll
            for (int fi = 0; fi < 4; ++fi)
                b[fi] = *(const bf16x8*)(bbase + (size_t)fi * 16 * (XN_STRIDE * 2) + kc * 64);
            #pragma unroll
            for (int mi = 0; mi < 4; ++mi)
                #pragma unroll
                for (int fi = 0; fi < 4; ++fi)
                    acc[mi][fi] = __builtin_amdgcn_mfma_f32_16x16x32_bf16(aA[mi], b[fi], acc[mi][fi], 0, 0, 0);
        }
        // prefetch kc+2
        if (kc + 2 < 16) {
            #pragma unroll
            for (int mi = 0; mi < 4; ++mi)
                aA[mi] = *(const bf16x8*)(wbase + (size_t)(kc + 2) * 16384 + (size_t)mi * 512);
        }
        {
            bf16x8 b[4];
            #pragma unroll
            for (int fi = 0; fi < 4; ++fi)
                b[fi] = *(const bf16x8*)(bbase + (size_t)fi * 16 * (XN_STRIDE * 2) + (kc + 1) * 64);
            #pragma unroll
            for (int mi = 0; mi < 4; ++mi)
                #pragma unroll
                for (int fi = 0; fi < 4; ++fi)
                    acc[mi][fi] = __builtin_amdgcn_mfma_f32_16x16x32_bf16(aB[mi], b[fi], acc[mi][fi], 0, 0, 0);
        }
    }

    // epilogue: bias + fast gelu + residual (x re-read L3-resident: same tile)
    #pragma unroll
    for (int mi = 0; mi < 4; ++mi) {
        const int mbase = w * 64 + mi * 16 + q4 * 4;
        #pragma unroll
        for (int r = 0; r < 4; ++r) {
            const int m = mbase + r;
            const float bv = bias[m];
            #pragma unroll
            for (int fi = 0; fi < 4; ++fi) {
                float y = acc[mi][fi][r] + bv;
                float gl = gelu_fast(y);
                size_t o = ((size_t)(batch * 512 + m)) * 512 + (size_t)(f0 + fi * 16 + lr);
                out[o] = gl + x[o];
            }
        }
    }
}

extern "C" void kernel_launch(void* const* d_in, const int* in_sizes, int n_in,
                              void* d_out, int out_size, void* d_ws, size_t ws_size,
                              hipStream_t stream) {
    const float* x     = (const float*)d_in[0];
    const float* gamma = (const float*)d_in[1];
    const float* beta  = (const float*)d_in[2];
    const float* W     = (const float*)d_in[3];
    const float* bias  = (const float*)d_in[4];
    float* out = (float*)d_out;
    unsigned short* Wq = (unsigned short*)d_ws;  // 512 KB fragment-major bf16 W

    wconv_kernel<<<dim3(128), 256, 0, stream>>>(W, Wq);
    dim3 grid(F_ / FT, B_);
    timemix_main<<<grid, 512, 0, stream>>>(x, gamma, beta, Wq, bias, out);
}